// Round 2
// baseline (53.619 us; speedup 1.0000x reference)
//
#include <hip/hip_runtime.h>

// 3x3 median filter, stride 1, reflect padding ("same"), NCHW fp32.
// Input: 32 x 3 x 512 x 512 fp32. Output: same shape.
//
// Separable median-of-9: sort each column of 3 (lo/mi/hi via min3/med3/max3),
// then out = med3( max3(lo), med3(mi), min3(hi) ). Column sorts shared across
// the 8 outputs each thread produces -> ~12 VALU ops/output vs 38 for the
// Paeth network.

#define IMG_H 512
#define IMG_W 512

__device__ __forceinline__ float min3f(float a, float b, float c) {
    return fminf(fminf(a, b), c);
}
__device__ __forceinline__ float max3f(float a, float b, float c) {
    return fmaxf(fmaxf(a, b), c);
}
__device__ __forceinline__ float med3f(float a, float b, float c) {
    return __builtin_amdgcn_fmed3f(a, b, c);   // v_med3_f32
}

__global__ __launch_bounds__(256) void median3x3_kernel(
        const float* __restrict__ in, float* __restrict__ out, int nplanes) {
    const int GROUPS = IMG_W / 8;            // 64 groups of 8 cols per row
    int gid = blockIdx.x * blockDim.x + threadIdx.x;
    int row = gid / GROUPS;
    int x0  = (gid % GROUPS) * 8;            // first of 8 output columns
    int plane = row >> 9;                    // row / 512
    int y     = row & (IMG_H - 1);
    if (plane >= nplanes) return;

    const float* base = in + (size_t)plane * IMG_H * IMG_W;
    // reflect-pad row indices (pad=1): -1 -> 1, H -> H-2
    int ym = (y == 0)         ? 1         : y - 1;
    int yp = (y == IMG_H - 1) ? IMG_H - 2 : y + 1;
    const float* r0 = base + (size_t)ym * IMG_W;
    const float* r1 = base + (size_t)y  * IMG_W;
    const float* r2 = base + (size_t)yp * IMG_W;

    // reflect-pad column indices for the two edge taps
    int xm = (x0 == 0)           ? 1         : x0 - 1;   // col x0-1
    int xr = (x0 + 8 == IMG_W)   ? IMG_W - 2 : x0 + 8;   // col x0+8

    // 8 aligned vector loads + 6 edge scalars, all issued up front (MLP)
    float4 a0 = *reinterpret_cast<const float4*>(r0 + x0);
    float4 a1 = *reinterpret_cast<const float4*>(r0 + x0 + 4);
    float4 b0 = *reinterpret_cast<const float4*>(r1 + x0);
    float4 b1 = *reinterpret_cast<const float4*>(r1 + x0 + 4);
    float4 c0 = *reinterpret_cast<const float4*>(r2 + x0);
    float4 c1 = *reinterpret_cast<const float4*>(r2 + x0 + 4);
    float aL = r0[xm], aR = r0[xr];
    float bL = r1[xm], bR = r1[xr];
    float cL = r2[xm], cR = r2[xr];

    float A[10] = {aL, a0.x, a0.y, a0.z, a0.w, a1.x, a1.y, a1.z, a1.w, aR};
    float B[10] = {bL, b0.x, b0.y, b0.z, b0.w, b1.x, b1.y, b1.z, b1.w, bR};
    float C[10] = {cL, c0.x, c0.y, c0.z, c0.w, c1.x, c1.y, c1.z, c1.w, cR};

    float lo[10], mi[10], hi[10];
#pragma unroll
    for (int i = 0; i < 10; ++i) {
        lo[i] = min3f(A[i], B[i], C[i]);
        mi[i] = med3f(A[i], B[i], C[i]);
        hi[i] = max3f(A[i], B[i], C[i]);
    }

    float o[8];
#pragma unroll
    for (int i = 0; i < 8; ++i) {
        o[i] = med3f(max3f(lo[i], lo[i + 1], lo[i + 2]),
                     med3f(mi[i], mi[i + 1], mi[i + 2]),
                     min3f(hi[i], hi[i + 1], hi[i + 2]));
    }

    float* orow = out + (size_t)plane * IMG_H * IMG_W + (size_t)y * IMG_W;
    *reinterpret_cast<float4*>(orow + x0)     = make_float4(o[0], o[1], o[2], o[3]);
    *reinterpret_cast<float4*>(orow + x0 + 4) = make_float4(o[4], o[5], o[6], o[7]);
}

extern "C" void kernel_launch(void* const* d_in, const int* in_sizes, int n_in,
                              void* d_out, int out_size, void* d_ws, size_t ws_size,
                              hipStream_t stream) {
    const float* x = (const float*)d_in[0];
    float* out = (float*)d_out;
    int nplanes = in_sizes[0] / (IMG_H * IMG_W);        // 32*3 = 96

    int total_threads = nplanes * IMG_H * (IMG_W / 8);  // 3,145,728
    int block = 256;
    int grid = (total_threads + block - 1) / block;     // 12,288
    median3x3_kernel<<<grid, block, 0, stream>>>(x, out, nplanes);
}

// Round 3
// 40.783 us; speedup vs baseline: 1.3147x; 1.3147x over previous
//
#include <hip/hip_runtime.h>

// 3x3 median filter, stride 1, reflect padding ("same"), NCHW fp32.
// Input: 32 x 3 x 512 x 512 fp32. Output: same shape.
//
// Each thread computes a 4-row x 8-col output patch:
//   - 12 float4 loads (6 input rows x 32B) + 8 float4 stores = 20 VMEM / 32 out
//     (vs 2.0 VMEM/output in the previous version -> attacks VMEM-issue bound)
//   - horizontal edge taps come from neighbor lanes via shfl (a wave's 64
//     lanes cover exactly one 512-wide row), reflect at lane 0/63.
//   - median-of-9 is separable: sort3 each column (v_min3/v_med3/v_max3),
//     combine: med3(max3(lo), med3(mi), min3(hi)).

#define IMG_H 512
#define IMG_W 512

__device__ __forceinline__ float min3f(float a, float b, float c) {
    return fminf(fminf(a, b), c);
}
__device__ __forceinline__ float max3f(float a, float b, float c) {
    return fmaxf(fmaxf(a, b), c);
}
__device__ __forceinline__ float med3f(float a, float b, float c) {
    return __builtin_amdgcn_fmed3f(a, b, c);   // v_med3_f32
}

__global__ __launch_bounds__(256) void median3x3_kernel(
        const float* __restrict__ in, float* __restrict__ out, int nplanes) {
    const int lane = threadIdx.x & 63;                   // column group in row
    const int rowgroup = blockIdx.x * 4 + (threadIdx.x >> 6);
    const int plane = rowgroup >> 7;                     // / (512/4)
    const int y0 = (rowgroup & 127) * 4;                 // first of 4 out rows
    const int x0 = lane * 8;                             // first of 8 out cols
    if (plane >= nplanes) return;

    const size_t pbase = (size_t)plane * IMG_H * IMG_W;
    const float* bp = in + pbase;

    // 6 source rows y0-1 .. y0+4 with reflect at the image border
    int ys[6];
    ys[0] = (y0 == 0) ? 1 : y0 - 1;
    ys[1] = y0; ys[2] = y0 + 1; ys[3] = y0 + 2; ys[4] = y0 + 3;
    ys[5] = (y0 + 4 == IMG_H) ? IMG_H - 2 : y0 + 4;

    // issue all 12 vector loads up front
    float4 v0[6], v1[6];
#pragma unroll
    for (int k = 0; k < 6; ++k) {
        const float* r = bp + (size_t)ys[k] * IMG_W + x0;
        v0[k] = *reinterpret_cast<const float4*>(r);
        v1[k] = *reinterpret_cast<const float4*>(r + 4);
    }

    // horizontal edge taps from neighbor lanes (reflect at row ends)
    float L[6], R[6];
#pragma unroll
    for (int k = 0; k < 6; ++k) {
        float l  = __shfl_up(v1[k].w, 1);    // lane-1's col x0+7  (= col x0-1)
        float rr = __shfl_down(v0[k].x, 1);  // lane+1's col x0    (= col x0+8)
        L[k] = (lane == 0)  ? v0[k].y : l;   // reflect(-1) = col 1
        R[k] = (lane == 63) ? v1[k].z : rr;  // reflect(512) = col 510
    }

    float* op = out + pbase + (size_t)y0 * IMG_W + x0;
#pragma unroll
    for (int w = 0; w < 4; ++w) {
        const float A[10] = {L[w],     v0[w].x,   v0[w].y,   v0[w].z,   v0[w].w,
                             v1[w].x,  v1[w].y,   v1[w].z,   v1[w].w,   R[w]};
        const float B[10] = {L[w+1],   v0[w+1].x, v0[w+1].y, v0[w+1].z, v0[w+1].w,
                             v1[w+1].x, v1[w+1].y, v1[w+1].z, v1[w+1].w, R[w+1]};
        const float C[10] = {L[w+2],   v0[w+2].x, v0[w+2].y, v0[w+2].z, v0[w+2].w,
                             v1[w+2].x, v1[w+2].y, v1[w+2].z, v1[w+2].w, R[w+2]};

        float lo[10], mi[10], hi[10];
#pragma unroll
        for (int i = 0; i < 10; ++i) {
            lo[i] = min3f(A[i], B[i], C[i]);
            mi[i] = med3f(A[i], B[i], C[i]);
            hi[i] = max3f(A[i], B[i], C[i]);
        }
        float o[8];
#pragma unroll
        for (int i = 0; i < 8; ++i) {
            o[i] = med3f(max3f(lo[i], lo[i + 1], lo[i + 2]),
                         med3f(mi[i], mi[i + 1], mi[i + 2]),
                         min3f(hi[i], hi[i + 1], hi[i + 2]));
        }
        *reinterpret_cast<float4*>(op + (size_t)w * IMG_W)
            = make_float4(o[0], o[1], o[2], o[3]);
        *reinterpret_cast<float4*>(op + (size_t)w * IMG_W + 4)
            = make_float4(o[4], o[5], o[6], o[7]);
    }
}

extern "C" void kernel_launch(void* const* d_in, const int* in_sizes, int n_in,
                              void* d_out, int out_size, void* d_ws, size_t ws_size,
                              hipStream_t stream) {
    const float* x = (const float*)d_in[0];
    float* out = (float*)d_out;
    int nplanes = in_sizes[0] / (IMG_H * IMG_W);           // 32*3 = 96

    // one wave (64 lanes) per 4-row stripe; 4 waves per block
    int rowgroups = nplanes * (IMG_H / 4);                 // 12,288
    int grid = rowgroups / 4;                              // 3,072 blocks
    median3x3_kernel<<<grid, 256, 0, stream>>>(x, out, nplanes);
}